// Round 11
// baseline (137.573 us; speedup 1.0000x reference)
//
#include <hip/hip_runtime.h>
#include <hip/hip_bf16.h>

// STU spectral conv. out[b,t,d] = 2 * sum_{j even} phi_proj[j,d] x_proj[b,t-j,d].
// Even/odd time split packed as complex -> one FFT-4096 per (b,d).
// FFT-4096 = radix-16^3 register FFT, 256 threads, 16 cplx/thread.
// R11: (a) packed-asm complex helpers REVERTED to scalar (R10 A/B: neutral,
// marshaling ate the gain -- m240 pattern); (b) GEMM gets T4 counted-vmcnt
// pipeline: 3 rotating LDS buffers, loads for t+2 stay in flight across a raw
// s_barrier, s_waitcnt vmcnt(6) retires exactly tile t+1's 6 VMEM ops.
// Kills the per-iteration vmcnt(0) drain that left the R7 loop ~50% stalled.

#define NB 4
#define NS 4096
#define ND 768
#define NK 24

typedef __attribute__((ext_vector_type(8))) short short8;
typedef __attribute__((ext_vector_type(4))) float f32x4;
typedef __attribute__((ext_vector_type(4))) unsigned short u16x4;

static __device__ __forceinline__ float bf2f(unsigned short u) {
  union { unsigned int i; float f; } v; v.i = ((unsigned int)u) << 16; return v.f;
}
static __device__ __forceinline__ unsigned short f2bf(float f) {
  union { float f; unsigned int i; } v; v.f = f;
  return (unsigned short)((v.i + 0x7fffu + ((v.i >> 16) & 1u)) >> 16);
}

__device__ __forceinline__ float2 cadd(float2 a, float2 b){ return make_float2(a.x+b.x, a.y+b.y); }
__device__ __forceinline__ float2 csub(float2 a, float2 b){ return make_float2(a.x-b.x, a.y-b.y); }
__device__ __forceinline__ float2 cmul(float2 a, float2 b){ return make_float2(a.x*b.x-a.y*b.y, a.x*b.y+a.y*b.x); }
// a * conj(b)
__device__ __forceinline__ float2 cmulc(float2 a, float2 b){ return make_float2(a.x*b.x+a.y*b.y, a.y*b.x-a.x*b.y); }

#define C4 0.70710678118654752f
#define C8 0.92387953251128674f
#define S8 0.38268343236508977f
#define TWO_PI 6.28318530717958648f

// DIF 16-pt: natural input, output reg r holds X[bitrev4(r)]
__device__ __forceinline__ void fft16_dif(float2 v[16]) {
  const float twr[8] = {1.f, C8, C4, S8, 0.f, -S8, -C4, -C8};
  const float twi[8] = {0.f, -S8, -C4, -C8, -1.f, -C8, -C4, -S8};
#pragma unroll
  for (int i = 0; i < 8; ++i) {                       // m=8
    float2 a = v[i], b = v[i+8];
    v[i] = cadd(a, b);
    float2 d = csub(a, b);
    v[i+8] = make_float2(d.x*twr[i]-d.y*twi[i], d.x*twi[i]+d.y*twr[i]);
  }
#pragma unroll
  for (int blk = 0; blk < 16; blk += 8)               // m=4
#pragma unroll
    for (int i = 0; i < 4; ++i) {
      float2 a = v[blk+i], b = v[blk+i+4];
      v[blk+i] = cadd(a, b);
      float2 d = csub(a, b);
      v[blk+i+4] = make_float2(d.x*twr[2*i]-d.y*twi[2*i], d.x*twi[2*i]+d.y*twr[2*i]);
    }
#pragma unroll
  for (int blk = 0; blk < 16; blk += 4) {             // m=2 (tw: 1, -i)
    { float2 a = v[blk],   b = v[blk+2]; v[blk] = cadd(a,b);   v[blk+2] = csub(a,b); }
    { float2 a = v[blk+1], b = v[blk+3]; float2 d = csub(a,b);
      v[blk+1] = cadd(a,b); v[blk+3] = make_float2(d.y, -d.x); }
  }
#pragma unroll
  for (int blk = 0; blk < 16; blk += 2) {             // m=1
    float2 a = v[blk], b = v[blk+1];
    v[blk] = cadd(a, b); v[blk+1] = csub(a, b);
  }
}

// same but input v[8..15] known zero (zero-padded signal)
__device__ __forceinline__ void fft16_dif_zero8(float2 v[16]) {
  const float twr[8] = {1.f, C8, C4, S8, 0.f, -S8, -C4, -C8};
  const float twi[8] = {0.f, -S8, -C4, -C8, -1.f, -C8, -C4, -S8};
#pragma unroll
  for (int i = 1; i < 8; ++i) {                       // m=8, b=0
    float2 a = v[i];
    v[i+8] = make_float2(a.x*twr[i]-a.y*twi[i], a.x*twi[i]+a.y*twr[i]);
  }
  v[8] = v[0];
#pragma unroll
  for (int blk = 0; blk < 16; blk += 8)               // m=4
#pragma unroll
    for (int i = 0; i < 4; ++i) {
      float2 a = v[blk+i], b = v[blk+i+4];
      v[blk+i] = cadd(a, b);
      float2 d = csub(a, b);
      v[blk+i+4] = make_float2(d.x*twr[2*i]-d.y*twi[2*i], d.x*twi[2*i]+d.y*twr[2*i]);
    }
#pragma unroll
  for (int blk = 0; blk < 16; blk += 4) {             // m=2
    { float2 a = v[blk],   b = v[blk+2]; v[blk] = cadd(a,b);   v[blk+2] = csub(a,b); }
    { float2 a = v[blk+1], b = v[blk+3]; float2 d = csub(a,b);
      v[blk+1] = cadd(a,b); v[blk+3] = make_float2(d.y, -d.x); }
  }
#pragma unroll
  for (int blk = 0; blk < 16; blk += 2) {             // m=1
    float2 a = v[blk], b = v[blk+1];
    v[blk] = cadd(a, b); v[blk+1] = csub(a, b);
  }
}

// conj-transpose mirror (unnormalized): input reg r = X[bitrev4(r)],
// output natural y[n] = sum_k X[k] W^{+nk}
__device__ __forceinline__ void idft16(float2 v[16]) {
  const float twr[8] = {1.f, C8, C4, S8, 0.f, -S8, -C4, -C8};
  const float twi[8] = {0.f, S8, C4, C8, 1.f, C8, C4, S8};     // conj
#pragma unroll
  for (int blk = 0; blk < 16; blk += 2) {             // m=1
    float2 a = v[blk], b = v[blk+1];
    v[blk] = cadd(a, b); v[blk+1] = csub(a, b);
  }
#pragma unroll
  for (int blk = 0; blk < 16; blk += 4) {             // m=2 (tw: 1, +i)
    { float2 a = v[blk],   b = v[blk+2]; v[blk] = cadd(a,b);   v[blk+2] = csub(a,b); }
    { float2 a = v[blk+1], b = v[blk+3]; float2 t = make_float2(-b.y, b.x);
      v[blk+1] = cadd(a,t); v[blk+3] = csub(a,t); }
  }
#pragma unroll
  for (int blk = 0; blk < 16; blk += 8)               // m=4
#pragma unroll
    for (int i = 0; i < 4; ++i) {
      float2 b = v[blk+i+4];
      float2 t = make_float2(b.x*twr[2*i]-b.y*twi[2*i], b.x*twi[2*i]+b.y*twr[2*i]);
      float2 a = v[blk+i];
      v[blk+i] = cadd(a, t); v[blk+i+4] = csub(a, t);
    }
#pragma unroll
  for (int i = 0; i < 8; ++i) {                       // m=8
    float2 b = v[i+8];
    float2 t = make_float2(b.x*twr[i]-b.y*twi[i], b.x*twi[i]+b.y*twr[i]);
    float2 a = v[i];
    v[i] = cadd(a, t); v[i+8] = csub(a, t);
  }
}

// idft16 but only outputs 0..7 needed: last stage skips subtract half
__device__ __forceinline__ void idft16_low8(float2 v[16]) {
  const float twr[8] = {1.f, C8, C4, S8, 0.f, -S8, -C4, -C8};
  const float twi[8] = {0.f, S8, C4, C8, 1.f, C8, C4, S8};
#pragma unroll
  for (int blk = 0; blk < 16; blk += 2) {
    float2 a = v[blk], b = v[blk+1];
    v[blk] = cadd(a, b); v[blk+1] = csub(a, b);
  }
#pragma unroll
  for (int blk = 0; blk < 16; blk += 4) {
    { float2 a = v[blk],   b = v[blk+2]; v[blk] = cadd(a,b);   v[blk+2] = csub(a,b); }
    { float2 a = v[blk+1], b = v[blk+3]; float2 t = make_float2(-b.y, b.x);
      v[blk+1] = cadd(a,t); v[blk+3] = csub(a,t); }
  }
#pragma unroll
  for (int blk = 0; blk < 16; blk += 8)
#pragma unroll
    for (int i = 0; i < 4; ++i) {
      float2 b = v[blk+i+4];
      float2 t = make_float2(b.x*twr[2*i]-b.y*twi[2*i], b.x*twi[2*i]+b.y*twr[2*i]);
      float2 a = v[blk+i];
      v[blk+i] = cadd(a, t); v[blk+i+4] = csub(a, t);
    }
#pragma unroll
  for (int i = 0; i < 8; ++i) {                       // m=8: only y[i]=a+t
    float2 b = v[i+8];
    float2 t = make_float2(b.x*twr[i]-b.y*twi[i], b.x*twi[i]+b.y*twr[i]);
    v[i] = cadd(v[i], t);
  }
}

#define BR_TABLE {0,8,4,12,2,10,6,14,1,9,5,13,3,11,7,15}
#define PAD(i) ((i) + ((i) >> 4))

// ---------------- MiT[d][e] = bf16(Mi[e][d]), LDS-tiled ----------------
__global__ __launch_bounds__(256) void transpose_cast_Mi(const float* __restrict__ Mi,
                                                         unsigned short* __restrict__ MiT) {
  __shared__ float tile[64][65];
  const int d0 = blockIdx.x * 64;
  const int e0 = blockIdx.y * 64;
  const int tid = threadIdx.x;
#pragma unroll
  for (int i = 0; i < 16; ++i) {
    int ee = (tid >> 6) + i * 4;
    int dd = tid & 63;
    tile[ee][dd] = Mi[(e0 + ee) * ND + d0 + dd];
  }
  __syncthreads();
#pragma unroll
  for (int i = 0; i < 8; ++i) {
    int dd = (tid >> 5) + i * 8;
    int ee2 = (tid & 31) * 2;
    unsigned int w = (unsigned int)f2bf(tile[ee2][dd]) |
                     ((unsigned int)f2bf(tile[ee2 + 1][dd]) << 16);
    *(unsigned int*)(MiT + (size_t)(d0 + dd) * ND + e0 + ee2) = w;
  }
}

// ---------------- GEMM: counted-vmcnt pipelined (T4), 3 LDS buffers ----------------
// Per iter t: issue A-loads(t+2)->regs + B-gload_lds(t+2); ds_read+MFMA on
// buf[t%3]; s_waitcnt vmcnt(6) retires tile t+1's 6 VMEM ops (t+2's stay in
// flight); pack+ds_write A(t+1); lgkmcnt(0); raw s_barrier. Reg sets pA/pB
// alternate statically (unroll-2). WAR on buf[(t+2)%3] safe: its readers
// (iter t-1) finished before the previous barrier.
#define GEMM_ISSUE(T, LDRG)                                                    \
  {                                                                            \
    const int nxt = ((T) + 2) % 3;                                             \
    const int k0n = ((T) + 2) * 32;                                            \
    const float* ga = Xf + (size_t)(r0 + rowA) * ND + k0n + colq;              \
    LDRG[0] = *(const float4*)ga; LDRG[1] = *(const float4*)(ga + 4);          \
    const float* ga2 = ga + (size_t)64 * ND;                                   \
    LDRG[2] = *(const float4*)ga2; LDRG[3] = *(const float4*)(ga2 + 4);        \
    unsigned short* Bn = (unsigned short*)(smem + nxt * 16384) + 4096;         \
    _Pragma("unroll")                                                          \
    for (int h = 0; h < 2; ++h) {                                              \
      int c = wave * 2 + h;                                                    \
      int rowc = c * 16 + (lane >> 2);                                         \
      const unsigned short* gb = MiT + (size_t)(c0 + rowc) * ND + k0n + (lane & 3) * 8; \
      __builtin_amdgcn_global_load_lds(                                        \
          (const __attribute__((address_space(1))) void*)gb,                   \
          (__attribute__((address_space(3))) void*)(Bn + c * 512), 16, 0, 0);  \
    }                                                                          \
  }

#define GEMM_COMPUTE(T)                                                        \
  {                                                                            \
    const int cur = (T) % 3;                                                   \
    unsigned short* Ac = (unsigned short*)(smem + cur * 16384);                \
    unsigned short* Bc = Ac + 4096;                                            \
    short8 a[4], b[4];                                                         \
    _Pragma("unroll")                                                          \
    for (int m = 0; m < 4; ++m)                                                \
      a[m] = *(const short8*)(Ac + (wr + m * 16 + (lane & 15)) * 32 + (lane >> 4) * 8); \
    _Pragma("unroll")                                                          \
    for (int n = 0; n < 4; ++n)                                                \
      b[n] = *(const short8*)(Bc + (wc + n * 16 + (lane & 15)) * 32 + (lane >> 4) * 8); \
    _Pragma("unroll")                                                          \
    for (int m = 0; m < 4; ++m)                                                \
      _Pragma("unroll")                                                        \
      for (int n = 0; n < 4; ++n)                                              \
        acc[m][n] = __builtin_amdgcn_mfma_f32_16x16x32_bf16(a[m], b[n], acc[m][n], 0, 0, 0); \
  }

#define GEMM_PACK(T, PKRG)                                                     \
  {                                                                            \
    const int pkb = ((T) + 1) % 3;                                             \
    unsigned short* An = (unsigned short*)(smem + pkb * 16384);                \
    unsigned int w0 = (unsigned int)f2bf(PKRG[0].x) | ((unsigned int)f2bf(PKRG[0].y) << 16); \
    unsigned int w1 = (unsigned int)f2bf(PKRG[0].z) | ((unsigned int)f2bf(PKRG[0].w) << 16); \
    unsigned int w2 = (unsigned int)f2bf(PKRG[1].x) | ((unsigned int)f2bf(PKRG[1].y) << 16); \
    unsigned int w3 = (unsigned int)f2bf(PKRG[1].z) | ((unsigned int)f2bf(PKRG[1].w) << 16); \
    *(uint4*)(An + tid * 8) = make_uint4(w0, w1, w2, w3);                      \
    w0 = (unsigned int)f2bf(PKRG[2].x) | ((unsigned int)f2bf(PKRG[2].y) << 16); \
    w1 = (unsigned int)f2bf(PKRG[2].z) | ((unsigned int)f2bf(PKRG[2].w) << 16); \
    w2 = (unsigned int)f2bf(PKRG[3].x) | ((unsigned int)f2bf(PKRG[3].y) << 16); \
    w3 = (unsigned int)f2bf(PKRG[3].z) | ((unsigned int)f2bf(PKRG[3].w) << 16); \
    *(uint4*)(An + 2048 + tid * 8) = make_uint4(w0, w1, w2, w3);               \
  }

__global__ __launch_bounds__(256) void gemm_xprojT(const float* __restrict__ Xf,
                                                   const unsigned short* __restrict__ MiT,
                                                   unsigned short* __restrict__ XPT) {
  __shared__ __align__(16) unsigned char smem[49152];  // 3 x (A 8KB + B 8KB); epilogue Cb 33792B
  const int tid = threadIdx.x;
  const int lane = tid & 63;
  const int wave = tid >> 6;
  const int f = blockIdx.x;
  const int swz = (f & 7) * 96 + (f >> 3);   // bijective XCD swizzle (768 = 8*96)
  const int c0 = (swz % 6) * 128;            // d
  const int r0 = (swz / 6) * 128;            // global row in [0,16384)

  const int rowA = tid >> 2;                 // 0..63 (rows rowA, rowA+64)
  const int colq = (tid & 3) * 8;
  const int wr = (wave >> 1) * 64;
  const int wc = (wave & 1) * 64;

  f32x4 acc[4][4];
#pragma unroll
  for (int m = 0; m < 4; ++m)
#pragma unroll
    for (int n = 0; n < 4; ++n) acc[m][n] = (f32x4){0.f, 0.f, 0.f, 0.f};

  float4 pA[4], pB[4];

  // ---- prologue: tile0 fully staged; tile1 loads in flight ----
  {
    const float* ga = Xf + (size_t)(r0 + rowA) * ND + colq;
    float4 q0 = *(const float4*)ga, q1 = *(const float4*)(ga + 4);
    const float* ga2 = ga + (size_t)64 * ND;
    float4 q2 = *(const float4*)ga2, q3 = *(const float4*)(ga2 + 4);
    unsigned short* B0 = (unsigned short*)(smem) + 4096;
#pragma unroll
    for (int h = 0; h < 2; ++h) {
      int c = wave * 2 + h;
      int rowc = c * 16 + (lane >> 2);
      const unsigned short* gb = MiT + (size_t)(c0 + rowc) * ND + (lane & 3) * 8;
      __builtin_amdgcn_global_load_lds(
          (const __attribute__((address_space(1))) void*)gb,
          (__attribute__((address_space(3))) void*)(B0 + c * 512), 16, 0, 0);
    }
    {
      unsigned short* An = (unsigned short*)smem;
      unsigned int w0 = (unsigned int)f2bf(q0.x) | ((unsigned int)f2bf(q0.y) << 16);
      unsigned int w1 = (unsigned int)f2bf(q0.z) | ((unsigned int)f2bf(q0.w) << 16);
      unsigned int w2 = (unsigned int)f2bf(q1.x) | ((unsigned int)f2bf(q1.y) << 16);
      unsigned int w3 = (unsigned int)f2bf(q1.z) | ((unsigned int)f2bf(q1.w) << 16);
      *(uint4*)(An + tid * 8) = make_uint4(w0, w1, w2, w3);
      w0 = (unsigned int)f2bf(q2.x) | ((unsigned int)f2bf(q2.y) << 16);
      w1 = (unsigned int)f2bf(q2.z) | ((unsigned int)f2bf(q2.w) << 16);
      w2 = (unsigned int)f2bf(q3.x) | ((unsigned int)f2bf(q3.y) << 16);
      w3 = (unsigned int)f2bf(q3.z) | ((unsigned int)f2bf(q3.w) << 16);
      *(uint4*)(An + 2048 + tid * 8) = make_uint4(w0, w1, w2, w3);
    }
    // tile1 A-loads into pB + B-glds into buf1
    const float* gb1 = Xf + (size_t)(r0 + rowA) * ND + 32 + colq;
    pB[0] = *(const float4*)gb1; pB[1] = *(const float4*)(gb1 + 4);
    const float* gb2 = gb1 + (size_t)64 * ND;
    pB[2] = *(const float4*)gb2; pB[3] = *(const float4*)(gb2 + 4);
    unsigned short* B1 = (unsigned short*)(smem + 16384) + 4096;
#pragma unroll
    for (int h = 0; h < 2; ++h) {
      int c = wave * 2 + h;
      int rowc = c * 16 + (lane >> 2);
      const unsigned short* gb = MiT + (size_t)(c0 + rowc) * ND + 32 + (lane & 3) * 8;
      __builtin_amdgcn_global_load_lds(
          (const __attribute__((address_space(1))) void*)gb,
          (__attribute__((address_space(3))) void*)(B1 + c * 512), 16, 0, 0);
    }
    asm volatile("s_waitcnt vmcnt(6)" ::: "memory");   // retires B0 glds (A1/B1 in flight)
    asm volatile("s_waitcnt lgkmcnt(0)" ::: "memory"); // A0 ds_writes visible
    __builtin_amdgcn_s_barrier();
    asm volatile("" ::: "memory");
  }

  // ---- main loop: bodies 0..21 (always issue t+2), tails 22,23 ----
  for (int tt = 0; tt < 22; tt += 2) {
    GEMM_ISSUE(tt, pA);
    GEMM_COMPUTE(tt);
    asm volatile("s_waitcnt vmcnt(6)" ::: "memory");   // retires tile tt+1's loads
    GEMM_PACK(tt, pB);
    asm volatile("s_waitcnt lgkmcnt(0)" ::: "memory");
    __builtin_amdgcn_s_barrier();
    asm volatile("" ::: "memory");

    GEMM_ISSUE(tt + 1, pB);
    GEMM_COMPUTE(tt + 1);
    asm volatile("s_waitcnt vmcnt(6)" ::: "memory");
    GEMM_PACK(tt + 1, pA);
    asm volatile("s_waitcnt lgkmcnt(0)" ::: "memory");
    __builtin_amdgcn_s_barrier();
    asm volatile("" ::: "memory");
  }
  // t=22: no new issue; wait everything (tile 23's 6 ops), pack A(23)
  GEMM_COMPUTE(22);
  asm volatile("s_waitcnt vmcnt(0)" ::: "memory");
  GEMM_PACK(22, pB);
  asm volatile("s_waitcnt lgkmcnt(0)" ::: "memory");
  __builtin_amdgcn_s_barrier();
  asm volatile("" ::: "memory");
  // t=23: compute only
  GEMM_COMPUTE(23);

  __syncthreads();                      // full drain before reusing smem

  // epilogue: bf16-pack into LDS (pitch 66 dwords), then coalesced writes
  unsigned int* Cb = (unsigned int*)smem;   // [128 cols][66]
#pragma unroll
  for (int m = 0; m < 4; ++m)
#pragma unroll
    for (int n = 0; n < 4; ++n) {
      int col = wc + n * 16 + (lane & 15);
      int sp = (wr + m * 16 + (lane >> 4) * 4) >> 1;   // even
      f32x4 a4 = acc[m][n];
      unsigned int w0 = (unsigned int)f2bf(a4[0]) | ((unsigned int)f2bf(a4[1]) << 16);
      unsigned int w1 = (unsigned int)f2bf(a4[2]) | ((unsigned int)f2bf(a4[3]) << 16);
      *(uint2*)(Cb + col * 66 + sp) = make_uint2(w0, w1);
    }
  __syncthreads();
  const int bI = r0 >> 12;
  const int sBase = r0 & (NS - 1);
  {
    int col = tid >> 1, half = tid & 1;
    const unsigned int* srcl = Cb + col * 66 + half * 32;
    unsigned int* dstg = (unsigned int*)(XPT + ((size_t)bI * ND + c0 + col) * NS + sBase) + half * 32;
#pragma unroll
    for (int k = 0; k < 8; ++k)
      *(uint4*)(dstg + k * 4) = *(const uint4*)(srcl + k * 4);
  }
}

// ---------------- filter spectra (fused phi projection, LDS twiddle tables) ----------------
__global__ __launch_bounds__(256) void filter_fft(const float* __restrict__ phi,
                                                  const float* __restrict__ Mf,
                                                  float2* __restrict__ Hbr) {
  __shared__ float LR[4352], LI[4352];
  __shared__ float2 TA[256], TB[256];
  const int d = blockIdx.x;
  const int tid = threadIdx.x;
  const int BR[16] = BR_TABLE;
  float2 v[16];

  {
    float sn, cs;
    __sincosf(-(TWO_PI / 4096.f) * (float)tid, &sn, &cs); TA[tid] = make_float2(cs, sn);
    __sincosf(-(TWO_PI / 256.f) * (float)tid, &sn, &cs);  TB[tid] = make_float2(cs, sn);
  }

  float mf[NK];
#pragma unroll
  for (int k = 0; k < NK; ++k) mf[k] = Mf[k * ND + d];
#pragma unroll
  for (int n2 = 0; n2 < 8; ++n2) {
    int m = n2 * 256 + tid;            // 0..2047
    const float* pr = phi + (size_t)(2 * m) * NK;
    float acc = 0.f;
#pragma unroll
    for (int k = 0; k < NK; ++k) acc += pr[k] * mf[k];
    v[n2] = make_float2(acc, 0.f);
  }
#pragma unroll
  for (int n2 = 8; n2 < 16; ++n2) v[n2] = make_float2(0.f, 0.f);

  fft16_dif_zero8(v);
  __syncthreads();                     // tables ready
  const int t1 = tid >> 4, t0 = tid & 15;
#pragma unroll
  for (int p = 1; p < 16; ++p) v[BR[p]] = cmul(v[BR[p]], cmul(TB[p * t1], TA[p * t0]));
#pragma unroll
  for (int r = 0; r < 16; ++r) { int i = BR[r] * 256 + tid; int s = PAD(i); LR[s] = v[r].x; LI[s] = v[r].y; }
  __syncthreads();

  const int p2 = tid >> 4, n0 = tid & 15;
#pragma unroll
  for (int n1 = 0; n1 < 16; ++n1) { int i = p2 * 256 + n1 * 16 + n0; int s = PAD(i); v[n1] = make_float2(LR[s], LI[s]); }
  fft16_dif(v);
#pragma unroll
  for (int p = 1; p < 16; ++p) v[BR[p]] = cmul(v[BR[p]], TB[p * n0]);
  __syncthreads();
#pragma unroll
  for (int r = 0; r < 16; ++r) { int i = p2 * 256 + BR[r] * 16 + n0; int s = PAD(i); LR[s] = v[r].x; LI[s] = v[r].y; }
  __syncthreads();

#pragma unroll
  for (int q = 0; q < 16; ++q) { int i = tid * 16 + q; int s = PAD(i); v[q] = make_float2(LR[s], LI[s]); }
  fft16_dif(v);
  const float sc = 2.0f / 4096.0f;
  float2* H = Hbr + (size_t)d * 4096;
#pragma unroll
  for (int r = 0; r < 16; ++r)
    H[r * 256 + tid] = make_float2(v[r].x * sc, v[r].y * sc);
}

// ---------------- main conv: one (b,d) per workgroup ----------------
__global__ __launch_bounds__(256) void conv_kernel(const unsigned short* __restrict__ XPT,
                                                   const float2* __restrict__ Hbr,
                                                   unsigned int* __restrict__ outTb) {
  __shared__ float LR[4352], LI[4352];
  __shared__ float2 TA[256], TB[256];
  const int bd = blockIdx.x;
  const int d = bd % ND;
  const int tid = threadIdx.x;
  const int BR[16] = BR_TABLE;
  float2 v[16];

  {
    float sn, cs;
    __sincosf(-(TWO_PI / 4096.f) * (float)tid, &sn, &cs); TA[tid] = make_float2(cs, sn);
    __sincosf(-(TWO_PI / 256.f) * (float)tid, &sn, &cs);  TB[tid] = make_float2(cs, sn);
  }

  // load: z[n] = (x[2n], x[2n+1]) bf16 pair as one dword; n >= 2048 zero
  const unsigned int* src = (const unsigned int*)(XPT + (size_t)bd * NS);
#pragma unroll
  for (int n2 = 0; n2 < 8; ++n2) {
    unsigned int w = src[n2 * 256 + tid];
    v[n2] = make_float2(bf2f((unsigned short)(w & 0xffffu)), bf2f((unsigned short)(w >> 16)));
  }
#pragma unroll
  for (int n2 = 8; n2 < 16; ++n2) v[n2] = make_float2(0.f, 0.f);

  // ---- forward P1 ----
  fft16_dif_zero8(v);
  __syncthreads();                     // twiddle tables ready
  const int t1 = tid >> 4, t0 = tid & 15;
#pragma unroll
  for (int p = 1; p < 16; ++p) v[BR[p]] = cmul(v[BR[p]], cmul(TB[p * t1], TA[p * t0]));
#pragma unroll
  for (int r = 0; r < 16; ++r) { int i = BR[r] * 256 + tid; int s = PAD(i); LR[s] = v[r].x; LI[s] = v[r].y; }
  __syncthreads();

  // ---- forward P2 ----
  const int p2 = tid >> 4, n0 = tid & 15;
#pragma unroll
  for (int n1 = 0; n1 < 16; ++n1) { int i = p2 * 256 + n1 * 16 + n0; int s = PAD(i); v[n1] = make_float2(LR[s], LI[s]); }
  fft16_dif(v);
#pragma unroll
  for (int p = 1; p < 16; ++p) v[BR[p]] = cmul(v[BR[p]], TB[p * n0]);
  __syncthreads();
#pragma unroll
  for (int r = 0; r < 16; ++r) { int i = p2 * 256 + BR[r] * 16 + n0; int s = PAD(i); LR[s] = v[r].x; LI[s] = v[r].y; }
  __syncthreads();

  // ---- forward P3 + pointwise*H + inverse PA: all in registers ----
#pragma unroll
  for (int q = 0; q < 16; ++q) { int i = tid * 16 + q; int s = PAD(i); v[q] = make_float2(LR[s], LI[s]); }
  fft16_dif(v);
  const float2* H = Hbr + (size_t)d * 4096;
#pragma unroll
  for (int r = 0; r < 16; ++r) v[r] = cmul(v[r], H[r * 256 + tid]);
  idft16(v);                                   // -> natural over pc-axis
#pragma unroll
  for (int n = 1; n < 16; ++n) v[n] = cmulc(v[n], TB[n * (tid & 15)]);
#pragma unroll
  for (int n = 0; n < 16; ++n) { int i = tid * 16 + n; int s = PAD(i); LR[s] = v[n].x; LI[s] = v[n].y; }
  __syncthreads();

  // ---- inverse PB: thread (pa,n0), IDFT over pb -> n1 ----
#pragma unroll
  for (int r = 0; r < 16; ++r) { int i = p2 * 256 + BR[r] * 16 + n0; int s = PAD(i); v[r] = make_float2(LR[s], LI[s]); }
  idft16(v);                                   // -> natural n1
  {
    float2 cA = TA[p2 * n0];
#pragma unroll
    for (int n = 0; n < 16; ++n) v[n] = cmulc(v[n], cmul(TB[p2 * n], cA));
  }
  __syncthreads();
#pragma unroll
  for (int n = 0; n < 16; ++n) { int i = p2 * 256 + n * 16 + n0; int s = PAD(i); LR[s] = v[n].x; LI[s] = v[n].y; }
  __syncthreads();

  // ---- inverse PC: thread tid, IDFT over pa -> natural n2 (only n2<8 needed) ----
#pragma unroll
  for (int r = 0; r < 16; ++r) { int i = BR[r] * 256 + tid; int s = PAD(i); v[r] = make_float2(LR[s], LI[s]); }
  idft16_low8(v);
  unsigned int* dst = outTb + (size_t)bd * 2048;    // dword = (out[2n], out[2n+1]) bf16
#pragma unroll
  for (int n2 = 0; n2 < 8; ++n2) {
    float2 y = v[n2];
    unsigned int w = (unsigned int)f2bf(y.x) | ((unsigned int)f2bf(y.y) << 16);
    dst[(n2 << 8) + tid] = w;
  }
}

// ---------------- transpose outTb (B,D,S) bf16 -> out (B,S,D) fp32 ----------------
__global__ __launch_bounds__(256) void transpose_out(const unsigned int* __restrict__ outTb,
                                                     float* __restrict__ out) {
  __shared__ float tile[64][65];
  const int b = blockIdx.z;
  const int d0 = blockIdx.y * 64;
  const int s0 = blockIdx.x * 64;
  const int tid = threadIdx.x;
#pragma unroll
  for (int i = 0; i < 8; ++i) {
    int dd = (tid >> 5) + i * 8;
    int ss2 = (tid & 31) * 2;
    unsigned int w = outTb[(((size_t)b * ND + d0 + dd) * NS + s0 + ss2) >> 1];
    tile[dd][ss2]     = bf2f((unsigned short)(w & 0xffffu));
    tile[dd][ss2 + 1] = bf2f((unsigned short)(w >> 16));
  }
  __syncthreads();
#pragma unroll
  for (int i = 0; i < 16; ++i) {
    int ss = (tid >> 6) + i * 4;
    int dd = tid & 63;
    out[((size_t)b * NS + s0 + ss) * ND + d0 + dd] = tile[dd][ss];
  }
}

extern "C" void kernel_launch(void* const* d_in, const int* in_sizes, int n_in,
                              void* d_out, int out_size, void* d_ws, size_t ws_size,
                              hipStream_t stream) {
  const float* x   = (const float*)d_in[0];
  const float* phi = (const float*)d_in[1];
  const float* Mi  = (const float*)d_in[2];
  const float* Mf  = (const float*)d_in[3];
  float* out = (float*)d_out;

  // ws (96 MB): XPT bf16 @0 (24M) | Hbr @24M (24M) | pool @48M (48M)
  // pool: outTb bf16 @0 (24M) | MiT @24M
  const size_t SZ_XPT = (size_t)NB * ND * NS * 2;        // 24 MB
  const size_t SZ_HBR = (size_t)ND * 4096 * 8;           // 24 MB
  const size_t SZ_POOL = (size_t)NB * ND * NS * 4;       // 48 MB
  if (ws_size < SZ_XPT + SZ_HBR + SZ_POOL) return;

  char* ws = (char*)d_ws;
  unsigned short* xprojT = (unsigned short*)ws;
  float2* Hbr = (float2*)(ws + SZ_XPT);
  char* pool = ws + SZ_XPT + SZ_HBR;
  unsigned int* outTb = (unsigned int*)pool;
  unsigned short* MiT = (unsigned short*)(pool + 25165824);

  transpose_cast_Mi<<<dim3(ND / 64, ND / 64), 256, 0, stream>>>(Mi, MiT);
  gemm_xprojT<<<768, 256, 0, stream>>>(x, MiT, xprojT);
  filter_fft<<<ND, 256, 0, stream>>>(phi, Mf, Hbr);
  conv_kernel<<<NB * ND, 256, 0, stream>>>(xprojT, Hbr, outTb);
  transpose_out<<<dim3(NS / 64, ND / 64, NB), 256, 0, stream>>>(outTb, out);
}

// Round 12
// 128.170 us; speedup vs baseline: 1.0734x; 1.0734x over previous
//
#include <hip/hip_runtime.h>
#include <hip/hip_bf16.h>

// STU spectral conv. out[b,t,d] = 2 * sum_{j even} phi_proj[j,d] x_proj[b,t-j,d].
// Even/odd time split packed as complex -> one FFT-4096 per (b,d).
// FFT-4096 = radix-16^3 register FFT, 256 threads, 16 cplx/thread.
// R12: GEMM frozen at R7 verbatim (53us; R8/R9/R11 restructures all
// regressed -- structure is at its m102-measured envelope for this shape).
// Single delta: complex helpers as native <2 x float> ext-vector arithmetic
// (broadcast + shuffle idioms) so the backend folds them into VOP3P
// v_pk_add/mul/fma_f32 with op_sel/neg -- no inline asm (R10's marshaling
// trap), worst case scalar-equivalent.

#define NB 4
#define NS 4096
#define ND 768
#define NK 24

typedef __attribute__((ext_vector_type(8))) short short8;
typedef __attribute__((ext_vector_type(4))) float f32x4;
typedef __attribute__((ext_vector_type(2))) float f32x2;
typedef __attribute__((ext_vector_type(4))) unsigned short u16x4;

static __device__ __forceinline__ float bf2f(unsigned short u) {
  union { unsigned int i; float f; } v; v.i = ((unsigned int)u) << 16; return v.f;
}
static __device__ __forceinline__ unsigned short f2bf(float f) {
  union { float f; unsigned int i; } v; v.f = f;
  return (unsigned short)((v.i + 0x7fffu + ((v.i >> 16) & 1u)) >> 16);
}

// ---- complex primitives as <2 x float> vector math (backend -> VOP3P pk) ----
static __device__ __forceinline__ f32x2 c2v(float2 a){ return (f32x2){a.x, a.y}; }
static __device__ __forceinline__ float2 v2c(f32x2 a){ return make_float2(a[0], a[1]); }

__device__ __forceinline__ float2 cadd(float2 a, float2 b){ return v2c(c2v(a) + c2v(b)); }
__device__ __forceinline__ float2 csub(float2 a, float2 b){ return v2c(c2v(a) - c2v(b)); }
// (ax bx - ay by) + i(ax by + ay bx)
__device__ __forceinline__ float2 cmul(float2 a, float2 b){
  f32x2 av = c2v(a), bv = c2v(b);
  f32x2 bs = (f32x2){-bv[1], bv[0]};
  return v2c(bv * av[0] + bs * av[1]);
}
// a * conj(b) = (ax bx + ay by) + i(ay bx - ax by)
__device__ __forceinline__ float2 cmulc(float2 a, float2 b){
  f32x2 av = c2v(a), bv = c2v(b);
  f32x2 as = (f32x2){av[1], -av[0]};
  return v2c(av * bv[0] + as * bv[1]);
}
// d * (tr + i*ti), tr/ti compile-time consts
__device__ __forceinline__ float2 ctw(float2 d, float tr, float ti){
  f32x2 dv = c2v(d);
  f32x2 ds = (f32x2){-dv[1], dv[0]};
  return v2c(dv * tr + ds * ti);
}

#define C4 0.70710678118654752f
#define C8 0.92387953251128674f
#define S8 0.38268343236508977f
#define TWO_PI 6.28318530717958648f

// DIF 16-pt: natural input, output reg r holds X[bitrev4(r)]
__device__ __forceinline__ void fft16_dif(float2 v[16]) {
  const float twr[8] = {1.f, C8, C4, S8, 0.f, -S8, -C4, -C8};
  const float twi[8] = {0.f, -S8, -C4, -C8, -1.f, -C8, -C4, -S8};
#pragma unroll
  for (int i = 0; i < 8; ++i) {                       // m=8
    float2 a = v[i], b = v[i+8];
    v[i] = cadd(a, b);
    float2 d = csub(a, b);
    v[i+8] = ctw(d, twr[i], twi[i]);
  }
#pragma unroll
  for (int blk = 0; blk < 16; blk += 8)               // m=4
#pragma unroll
    for (int i = 0; i < 4; ++i) {
      float2 a = v[blk+i], b = v[blk+i+4];
      v[blk+i] = cadd(a, b);
      float2 d = csub(a, b);
      v[blk+i+4] = ctw(d, twr[2*i], twi[2*i]);
    }
#pragma unroll
  for (int blk = 0; blk < 16; blk += 4) {             // m=2 (tw: 1, -i)
    { float2 a = v[blk],   b = v[blk+2]; v[blk] = cadd(a,b);   v[blk+2] = csub(a,b); }
    { float2 a = v[blk+1], b = v[blk+3]; float2 d = csub(a,b);
      v[blk+1] = cadd(a,b); v[blk+3] = make_float2(d.y, -d.x); }
  }
#pragma unroll
  for (int blk = 0; blk < 16; blk += 2) {             // m=1
    float2 a = v[blk], b = v[blk+1];
    v[blk] = cadd(a, b); v[blk+1] = csub(a, b);
  }
}

// same but input v[8..15] known zero (zero-padded signal)
__device__ __forceinline__ void fft16_dif_zero8(float2 v[16]) {
  const float twr[8] = {1.f, C8, C4, S8, 0.f, -S8, -C4, -C8};
  const float twi[8] = {0.f, -S8, -C4, -C8, -1.f, -C8, -C4, -S8};
#pragma unroll
  for (int i = 1; i < 8; ++i) {                       // m=8, b=0
    v[i+8] = ctw(v[i], twr[i], twi[i]);
  }
  v[8] = v[0];
#pragma unroll
  for (int blk = 0; blk < 16; blk += 8)               // m=4
#pragma unroll
    for (int i = 0; i < 4; ++i) {
      float2 a = v[blk+i], b = v[blk+i+4];
      v[blk+i] = cadd(a, b);
      float2 d = csub(a, b);
      v[blk+i+4] = ctw(d, twr[2*i], twi[2*i]);
    }
#pragma unroll
  for (int blk = 0; blk < 16; blk += 4) {             // m=2
    { float2 a = v[blk],   b = v[blk+2]; v[blk] = cadd(a,b);   v[blk+2] = csub(a,b); }
    { float2 a = v[blk+1], b = v[blk+3]; float2 d = csub(a,b);
      v[blk+1] = cadd(a,b); v[blk+3] = make_float2(d.y, -d.x); }
  }
#pragma unroll
  for (int blk = 0; blk < 16; blk += 2) {             // m=1
    float2 a = v[blk], b = v[blk+1];
    v[blk] = cadd(a, b); v[blk+1] = csub(a, b);
  }
}

// conj-transpose mirror (unnormalized): input reg r = X[bitrev4(r)],
// output natural y[n] = sum_k X[k] W^{+nk}
__device__ __forceinline__ void idft16(float2 v[16]) {
  const float twr[8] = {1.f, C8, C4, S8, 0.f, -S8, -C4, -C8};
  const float twi[8] = {0.f, S8, C4, C8, 1.f, C8, C4, S8};     // conj
#pragma unroll
  for (int blk = 0; blk < 16; blk += 2) {             // m=1
    float2 a = v[blk], b = v[blk+1];
    v[blk] = cadd(a, b); v[blk+1] = csub(a, b);
  }
#pragma unroll
  for (int blk = 0; blk < 16; blk += 4) {             // m=2 (tw: 1, +i)
    { float2 a = v[blk],   b = v[blk+2]; v[blk] = cadd(a,b);   v[blk+2] = csub(a,b); }
    { float2 a = v[blk+1], b = v[blk+3]; float2 t = make_float2(-b.y, b.x);
      v[blk+1] = cadd(a,t); v[blk+3] = csub(a,t); }
  }
#pragma unroll
  for (int blk = 0; blk < 16; blk += 8)               // m=4
#pragma unroll
    for (int i = 0; i < 4; ++i) {
      float2 t = ctw(v[blk+i+4], twr[2*i], twi[2*i]);
      float2 a = v[blk+i];
      v[blk+i] = cadd(a, t); v[blk+i+4] = csub(a, t);
    }
#pragma unroll
  for (int i = 0; i < 8; ++i) {                       // m=8
    float2 t = ctw(v[i+8], twr[i], twi[i]);
    float2 a = v[i];
    v[i] = cadd(a, t); v[i+8] = csub(a, t);
  }
}

// idft16 but only outputs 0..7 needed: last stage skips subtract half
__device__ __forceinline__ void idft16_low8(float2 v[16]) {
  const float twr[8] = {1.f, C8, C4, S8, 0.f, -S8, -C4, -C8};
  const float twi[8] = {0.f, S8, C4, C8, 1.f, C8, C4, S8};
#pragma unroll
  for (int blk = 0; blk < 16; blk += 2) {
    float2 a = v[blk], b = v[blk+1];
    v[blk] = cadd(a, b); v[blk+1] = csub(a, b);
  }
#pragma unroll
  for (int blk = 0; blk < 16; blk += 4) {
    { float2 a = v[blk],   b = v[blk+2]; v[blk] = cadd(a,b);   v[blk+2] = csub(a,b); }
    { float2 a = v[blk+1], b = v[blk+3]; float2 t = make_float2(-b.y, b.x);
      v[blk+1] = cadd(a,t); v[blk+3] = csub(a,t); }
  }
#pragma unroll
  for (int blk = 0; blk < 16; blk += 8)
#pragma unroll
    for (int i = 0; i < 4; ++i) {
      float2 t = ctw(v[blk+i+4], twr[2*i], twi[2*i]);
      float2 a = v[blk+i];
      v[blk+i] = cadd(a, t); v[blk+i+4] = csub(a, t);
    }
#pragma unroll
  for (int i = 0; i < 8; ++i) {                       // m=8: only y[i]=a+t
    float2 t = ctw(v[i+8], twr[i], twi[i]);
    v[i] = cadd(v[i], t);
  }
}

#define BR_TABLE {0,8,4,12,2,10,6,14,1,9,5,13,3,11,7,15}
#define PAD(i) ((i) + ((i) >> 4))

// ---------------- MiT[d][e] = bf16(Mi[e][d]), LDS-tiled ----------------
__global__ __launch_bounds__(256) void transpose_cast_Mi(const float* __restrict__ Mi,
                                                         unsigned short* __restrict__ MiT) {
  __shared__ float tile[64][65];
  const int d0 = blockIdx.x * 64;
  const int e0 = blockIdx.y * 64;
  const int tid = threadIdx.x;
#pragma unroll
  for (int i = 0; i < 16; ++i) {
    int ee = (tid >> 6) + i * 4;
    int dd = tid & 63;
    tile[ee][dd] = Mi[(e0 + ee) * ND + d0 + dd];
  }
  __syncthreads();
#pragma unroll
  for (int i = 0; i < 8; ++i) {
    int dd = (tid >> 5) + i * 8;
    int ee2 = (tid & 31) * 2;
    unsigned int w = (unsigned int)f2bf(tile[ee2][dd]) |
                     ((unsigned int)f2bf(tile[ee2 + 1][dd]) << 16);
    *(unsigned int*)(MiT + (size_t)(d0 + dd) * ND + e0 + ee2) = w;
  }
}

// ---------------- GEMM (R7 verbatim: measured 53us, this shape's plateau) ----------------
__global__ __launch_bounds__(256) void gemm_xprojT(const float* __restrict__ Xf,
                                                   const unsigned short* __restrict__ MiT,
                                                   unsigned short* __restrict__ XPT) {
  __shared__ __align__(16) unsigned char smem[33792];   // dbuf A/B (32KB) or Cb (33KB)
  unsigned short* As0 = (unsigned short*)smem;          // 4096 shorts each
  unsigned short* Bs0 = As0 + 4096;
  unsigned short* As1 = Bs0 + 4096;
  unsigned short* Bs1 = As1 + 4096;

  const int tid = threadIdx.x;
  const int lane = tid & 63;
  const int wave = tid >> 6;
  const int f = blockIdx.x;
  const int swz = (f & 7) * 96 + (f >> 3);
  const int c0 = (swz % 6) * 128;       // d
  const int r0 = (swz / 6) * 128;       // global row in [0,16384)

  const int rowA = tid >> 2;            // 0..63
  const int colq = (tid & 3) * 8;       // 0,8,16,24

  f32x4 acc[4][4];
#pragma unroll
  for (int m = 0; m < 4; ++m)
#pragma unroll
    for (int n = 0; n < 4; ++n) acc[m][n] = (f32x4){0.f, 0.f, 0.f, 0.f};

  // ---- prologue: stage tile 0 into buf0 ----
  {
    const float* ga = Xf + (size_t)(r0 + rowA) * ND + colq;
    float4 p0 = *(const float4*)ga, p1 = *(const float4*)(ga + 4);
    const float* ga2 = ga + (size_t)64 * ND;
    float4 p2 = *(const float4*)ga2, p3 = *(const float4*)(ga2 + 4);
#pragma unroll
    for (int h = 0; h < 2; ++h) {
      int c = wave * 2 + h;
      int rowc = c * 16 + (lane >> 2);
      const unsigned short* gb = MiT + (size_t)(c0 + rowc) * ND + (lane & 3) * 8;
      __builtin_amdgcn_global_load_lds(
          (const __attribute__((address_space(1))) void*)gb,
          (__attribute__((address_space(3))) void*)(Bs0 + c * 512), 16, 0, 0);
    }
    unsigned int w0 = (unsigned int)f2bf(p0.x) | ((unsigned int)f2bf(p0.y) << 16);
    unsigned int w1 = (unsigned int)f2bf(p0.z) | ((unsigned int)f2bf(p0.w) << 16);
    unsigned int w2 = (unsigned int)f2bf(p1.x) | ((unsigned int)f2bf(p1.y) << 16);
    unsigned int w3 = (unsigned int)f2bf(p1.z) | ((unsigned int)f2bf(p1.w) << 16);
    *(uint4*)(As0 + tid * 8) = make_uint4(w0, w1, w2, w3);
    w0 = (unsigned int)f2bf(p2.x) | ((unsigned int)f2bf(p2.y) << 16);
    w1 = (unsigned int)f2bf(p2.z) | ((unsigned int)f2bf(p2.w) << 16);
    w2 = (unsigned int)f2bf(p3.x) | ((unsigned int)f2bf(p3.y) << 16);
    w3 = (unsigned int)f2bf(p3.z) | ((unsigned int)f2bf(p3.w) << 16);
    *(uint4*)(As0 + 2048 + tid * 8) = make_uint4(w0, w1, w2, w3);
  }
  __syncthreads();

  for (int t = 0; t < NK; ++t) {
    unsigned short* Ac = (t & 1) ? As1 : As0;
    unsigned short* Bc = (t & 1) ? Bs1 : Bs0;
    unsigned short* An = (t & 1) ? As0 : As1;
    unsigned short* Bn = (t & 1) ? Bs0 : Bs1;
    const bool pre = (t < NK - 1);
    float4 p0, p1, p2, p3;
    if (pre) {
      const int k0n = (t + 1) * 32;
      const float* ga = Xf + (size_t)(r0 + rowA) * ND + k0n + colq;
      p0 = *(const float4*)ga; p1 = *(const float4*)(ga + 4);
      const float* ga2 = ga + (size_t)64 * ND;
      p2 = *(const float4*)ga2; p3 = *(const float4*)(ga2 + 4);
#pragma unroll
      for (int h = 0; h < 2; ++h) {
        int c = wave * 2 + h;
        int rowc = c * 16 + (lane >> 2);
        const unsigned short* gb = MiT + (size_t)(c0 + rowc) * ND + k0n + (lane & 3) * 8;
        __builtin_amdgcn_global_load_lds(
            (const __attribute__((address_space(1))) void*)gb,
            (__attribute__((address_space(3))) void*)(Bn + c * 512), 16, 0, 0);
      }
    }

    const int wr = (wave >> 1) * 64;
    const int wc = (wave & 1) * 64;
    short8 a[4], b[4];
#pragma unroll
    for (int m = 0; m < 4; ++m)
      a[m] = *(const short8*)(Ac + (wr + m * 16 + (lane & 15)) * 32 + (lane >> 4) * 8);
#pragma unroll
    for (int n = 0; n < 4; ++n)
      b[n] = *(const short8*)(Bc + (wc + n * 16 + (lane & 15)) * 32 + (lane >> 4) * 8);
#pragma unroll
    for (int m = 0; m < 4; ++m)
#pragma unroll
      for (int n = 0; n < 4; ++n)
        acc[m][n] = __builtin_amdgcn_mfma_f32_16x16x32_bf16(a[m], b[n], acc[m][n], 0, 0, 0);

    if (pre) {
      unsigned int w0 = (unsigned int)f2bf(p0.x) | ((unsigned int)f2bf(p0.y) << 16);
      unsigned int w1 = (unsigned int)f2bf(p0.z) | ((unsigned int)f2bf(p0.w) << 16);
      unsigned int w2 = (unsigned int)f2bf(p1.x) | ((unsigned int)f2bf(p1.y) << 16);
      unsigned int w3 = (unsigned int)f2bf(p1.z) | ((unsigned int)f2bf(p1.w) << 16);
      *(uint4*)(An + tid * 8) = make_uint4(w0, w1, w2, w3);
      w0 = (unsigned int)f2bf(p2.x) | ((unsigned int)f2bf(p2.y) << 16);
      w1 = (unsigned int)f2bf(p2.z) | ((unsigned int)f2bf(p2.w) << 16);
      w2 = (unsigned int)f2bf(p3.x) | ((unsigned int)f2bf(p3.y) << 16);
      w3 = (unsigned int)f2bf(p3.z) | ((unsigned int)f2bf(p3.w) << 16);
      *(uint4*)(An + 2048 + tid * 8) = make_uint4(w0, w1, w2, w3);
      __syncthreads();
    }
  }
  __syncthreads();

  unsigned int* Cb = (unsigned int*)smem;   // [128 cols][66]
  const int wr = (wave >> 1) * 64;
  const int wc = (wave & 1) * 64;
#pragma unroll
  for (int m = 0; m < 4; ++m)
#pragma unroll
    for (int n = 0; n < 4; ++n) {
      int col = wc + n * 16 + (lane & 15);
      int sp = (wr + m * 16 + (lane >> 4) * 4) >> 1;   // even
      f32x4 a4 = acc[m][n];
      unsigned int w0 = (unsigned int)f2bf(a4[0]) | ((unsigned int)f2bf(a4[1]) << 16);
      unsigned int w1 = (unsigned int)f2bf(a4[2]) | ((unsigned int)f2bf(a4[3]) << 16);
      *(uint2*)(Cb + col * 66 + sp) = make_uint2(w0, w1);
    }
  __syncthreads();
  const int bI = r0 >> 12;
  const int sBase = r0 & (NS - 1);
  {
    int col = tid >> 1, half = tid & 1;
    const unsigned int* srcl = Cb + col * 66 + half * 32;
    unsigned int* dstg = (unsigned int*)(XPT + ((size_t)bI * ND + c0 + col) * NS + sBase) + half * 32;
#pragma unroll
    for (int k = 0; k < 8; ++k)
      *(uint4*)(dstg + k * 4) = *(const uint4*)(srcl + k * 4);
  }
}

// ---------------- filter spectra (fused phi projection, LDS twiddle tables) ----------------
__global__ __launch_bounds__(256) void filter_fft(const float* __restrict__ phi,
                                                  const float* __restrict__ Mf,
                                                  float2* __restrict__ Hbr) {
  __shared__ float LR[4352], LI[4352];
  __shared__ float2 TA[256], TB[256];
  const int d = blockIdx.x;
  const int tid = threadIdx.x;
  const int BR[16] = BR_TABLE;
  float2 v[16];

  {
    float sn, cs;
    __sincosf(-(TWO_PI / 4096.f) * (float)tid, &sn, &cs); TA[tid] = make_float2(cs, sn);
    __sincosf(-(TWO_PI / 256.f) * (float)tid, &sn, &cs);  TB[tid] = make_float2(cs, sn);
  }

  float mf[NK];
#pragma unroll
  for (int k = 0; k < NK; ++k) mf[k] = Mf[k * ND + d];
#pragma unroll
  for (int n2 = 0; n2 < 8; ++n2) {
    int m = n2 * 256 + tid;            // 0..2047
    const float* pr = phi + (size_t)(2 * m) * NK;
    float acc = 0.f;
#pragma unroll
    for (int k = 0; k < NK; ++k) acc += pr[k] * mf[k];
    v[n2] = make_float2(acc, 0.f);
  }
#pragma unroll
  for (int n2 = 8; n2 < 16; ++n2) v[n2] = make_float2(0.f, 0.f);

  fft16_dif_zero8(v);
  __syncthreads();                     // tables ready
  const int t1 = tid >> 4, t0 = tid & 15;
#pragma unroll
  for (int p = 1; p < 16; ++p) v[BR[p]] = cmul(v[BR[p]], cmul(TB[p * t1], TA[p * t0]));
#pragma unroll
  for (int r = 0; r < 16; ++r) { int i = BR[r] * 256 + tid; int s = PAD(i); LR[s] = v[r].x; LI[s] = v[r].y; }
  __syncthreads();

  const int p2 = tid >> 4, n0 = tid & 15;
#pragma unroll
  for (int n1 = 0; n1 < 16; ++n1) { int i = p2 * 256 + n1 * 16 + n0; int s = PAD(i); v[n1] = make_float2(LR[s], LI[s]); }
  fft16_dif(v);
#pragma unroll
  for (int p = 1; p < 16; ++p) v[BR[p]] = cmul(v[BR[p]], TB[p * n0]);
  __syncthreads();
#pragma unroll
  for (int r = 0; r < 16; ++r) { int i = p2 * 256 + BR[r] * 16 + n0; int s = PAD(i); LR[s] = v[r].x; LI[s] = v[r].y; }
  __syncthreads();

#pragma unroll
  for (int q = 0; q < 16; ++q) { int i = tid * 16 + q; int s = PAD(i); v[q] = make_float2(LR[s], LI[s]); }
  fft16_dif(v);
  const float sc = 2.0f / 4096.0f;
  float2* H = Hbr + (size_t)d * 4096;
#pragma unroll
  for (int r = 0; r < 16; ++r)
    H[r * 256 + tid] = make_float2(v[r].x * sc, v[r].y * sc);
}

// ---------------- main conv: one (b,d) per workgroup ----------------
__global__ __launch_bounds__(256) void conv_kernel(const unsigned short* __restrict__ XPT,
                                                   const float2* __restrict__ Hbr,
                                                   unsigned int* __restrict__ outTb) {
  __shared__ float LR[4352], LI[4352];
  __shared__ float2 TA[256], TB[256];
  const int bd = blockIdx.x;
  const int d = bd % ND;
  const int tid = threadIdx.x;
  const int BR[16] = BR_TABLE;
  float2 v[16];

  {
    float sn, cs;
    __sincosf(-(TWO_PI / 4096.f) * (float)tid, &sn, &cs); TA[tid] = make_float2(cs, sn);
    __sincosf(-(TWO_PI / 256.f) * (float)tid, &sn, &cs);  TB[tid] = make_float2(cs, sn);
  }

  // load: z[n] = (x[2n], x[2n+1]) bf16 pair as one dword; n >= 2048 zero
  const unsigned int* src = (const unsigned int*)(XPT + (size_t)bd * NS);
#pragma unroll
  for (int n2 = 0; n2 < 8; ++n2) {
    unsigned int w = src[n2 * 256 + tid];
    v[n2] = make_float2(bf2f((unsigned short)(w & 0xffffu)), bf2f((unsigned short)(w >> 16)));
  }
#pragma unroll
  for (int n2 = 8; n2 < 16; ++n2) v[n2] = make_float2(0.f, 0.f);

  // ---- forward P1 ----
  fft16_dif_zero8(v);
  __syncthreads();                     // twiddle tables ready
  const int t1 = tid >> 4, t0 = tid & 15;
#pragma unroll
  for (int p = 1; p < 16; ++p) v[BR[p]] = cmul(v[BR[p]], cmul(TB[p * t1], TA[p * t0]));
#pragma unroll
  for (int r = 0; r < 16; ++r) { int i = BR[r] * 256 + tid; int s = PAD(i); LR[s] = v[r].x; LI[s] = v[r].y; }
  __syncthreads();

  // ---- forward P2 ----
  const int p2 = tid >> 4, n0 = tid & 15;
#pragma unroll
  for (int n1 = 0; n1 < 16; ++n1) { int i = p2 * 256 + n1 * 16 + n0; int s = PAD(i); v[n1] = make_float2(LR[s], LI[s]); }
  fft16_dif(v);
#pragma unroll
  for (int p = 1; p < 16; ++p) v[BR[p]] = cmul(v[BR[p]], TB[p * n0]);
  __syncthreads();
#pragma unroll
  for (int r = 0; r < 16; ++r) { int i = p2 * 256 + BR[r] * 16 + n0; int s = PAD(i); LR[s] = v[r].x; LI[s] = v[r].y; }
  __syncthreads();

  // ---- forward P3 + pointwise*H + inverse PA: all in registers ----
#pragma unroll
  for (int q = 0; q < 16; ++q) { int i = tid * 16 + q; int s = PAD(i); v[q] = make_float2(LR[s], LI[s]); }
  fft16_dif(v);
  const float2* H = Hbr + (size_t)d * 4096;
#pragma unroll
  for (int r = 0; r < 16; ++r) v[r] = cmul(v[r], H[r * 256 + tid]);
  idft16(v);                                   // -> natural over pc-axis
#pragma unroll
  for (int n = 1; n < 16; ++n) v[n] = cmulc(v[n], TB[n * (tid & 15)]);
#pragma unroll
  for (int n = 0; n < 16; ++n) { int i = tid * 16 + n; int s = PAD(i); LR[s] = v[n].x; LI[s] = v[n].y; }
  __syncthreads();

  // ---- inverse PB: thread (pa,n0), IDFT over pb -> n1 ----
#pragma unroll
  for (int r = 0; r < 16; ++r) { int i = p2 * 256 + BR[r] * 16 + n0; int s = PAD(i); v[r] = make_float2(LR[s], LI[s]); }
  idft16(v);                                   // -> natural n1
  {
    float2 cA = TA[p2 * n0];
#pragma unroll
    for (int n = 0; n < 16; ++n) v[n] = cmulc(v[n], cmul(TB[p2 * n], cA));
  }
  __syncthreads();
#pragma unroll
  for (int n = 0; n < 16; ++n) { int i = p2 * 256 + n * 16 + n0; int s = PAD(i); LR[s] = v[n].x; LI[s] = v[n].y; }
  __syncthreads();

  // ---- inverse PC: thread tid, IDFT over pa -> natural n2 (only n2<8 needed) ----
#pragma unroll
  for (int r = 0; r < 16; ++r) { int i = BR[r] * 256 + tid; int s = PAD(i); v[r] = make_float2(LR[s], LI[s]); }
  idft16_low8(v);
  unsigned int* dst = outTb + (size_t)bd * 2048;    // dword = (out[2n], out[2n+1]) bf16
#pragma unroll
  for (int n2 = 0; n2 < 8; ++n2) {
    float2 y = v[n2];
    unsigned int w = (unsigned int)f2bf(y.x) | ((unsigned int)f2bf(y.y) << 16);
    dst[(n2 << 8) + tid] = w;
  }
}

// ---------------- transpose outTb (B,D,S) bf16 -> out (B,S,D) fp32 ----------------
__global__ __launch_bounds__(256) void transpose_out(const unsigned int* __restrict__ outTb,
                                                     float* __restrict__ out) {
  __shared__ float tile[64][65];
  const int b = blockIdx.z;
  const int d0 = blockIdx.y * 64;
  const int s0 = blockIdx.x * 64;
  const int tid = threadIdx.x;
#pragma unroll
  for (int i = 0; i < 8; ++i) {
    int dd = (tid >> 5) + i * 8;
    int ss2 = (tid & 31) * 2;
    unsigned int w = outTb[(((size_t)b * ND + d0 + dd) * NS + s0 + ss2) >> 1];
    tile[dd][ss2]     = bf2f((unsigned short)(w & 0xffffu));
    tile[dd][ss2 + 1] = bf2f((unsigned short)(w >> 16));
  }
  __syncthreads();
#pragma unroll
  for (int i = 0; i < 16; ++i) {
    int ss = (tid >> 6) + i * 4;
    int dd = tid & 63;
    out[((size_t)b * NS + s0 + ss) * ND + d0 + dd] = tile[dd][ss];
  }
}

extern "C" void kernel_launch(void* const* d_in, const int* in_sizes, int n_in,
                              void* d_out, int out_size, void* d_ws, size_t ws_size,
                              hipStream_t stream) {
  const float* x   = (const float*)d_in[0];
  const float* phi = (const float*)d_in[1];
  const float* Mi  = (const float*)d_in[2];
  const float* Mf  = (const float*)d_in[3];
  float* out = (float*)d_out;

  // ws (96 MB): XPT bf16 @0 (24M) | Hbr @24M (24M) | pool @48M (48M)
  // pool: outTb bf16 @0 (24M) | MiT @24M
  const size_t SZ_XPT = (size_t)NB * ND * NS * 2;        // 24 MB
  const size_t SZ_HBR = (size_t)ND * 4096 * 8;           // 24 MB
  const size_t SZ_POOL = (size_t)NB * ND * NS * 4;       // 48 MB
  if (ws_size < SZ_XPT + SZ_HBR + SZ_POOL) return;

  char* ws = (char*)d_ws;
  unsigned short* xprojT = (unsigned short*)ws;
  float2* Hbr = (float2*)(ws + SZ_XPT);
  char* pool = ws + SZ_XPT + SZ_HBR;
  unsigned int* outTb = (unsigned int*)pool;
  unsigned short* MiT = (unsigned short*)(pool + 25165824);

  transpose_cast_Mi<<<dim3(ND / 64, ND / 64), 256, 0, stream>>>(Mi, MiT);
  gemm_xprojT<<<768, 256, 0, stream>>>(x, MiT, xprojT);
  filter_fft<<<ND, 256, 0, stream>>>(phi, Mf, Hbr);
  conv_kernel<<<NB * ND, 256, 0, stream>>>(xprojT, Hbr, outTb);
  transpose_out<<<dim3(NS / 64, ND / 64, NB), 256, 0, stream>>>(outTb, out);
}

// Round 13
// 121.792 us; speedup vs baseline: 1.1296x; 1.0524x over previous
//
#include <hip/hip_runtime.h>
#include <hip/hip_bf16.h>

// STU spectral conv. out[b,t,d] = 2 * sum_{j even} phi_proj[j,d] x_proj[b,t-j,d].
// Even/odd time split packed as complex -> one FFT-4096 per (b,d).
// FFT-4096 = radix-16^3 register FFT, 256 threads, 16 cplx/thread.
// R13: helpers reverted to plain scalar (R10 asm and R12 ext-vector both
// neutral). Single delta: all fp32->bf16 packing via hardware
// v_cvt_pk_bf16_f32 (1 instr per pair, replaces 6-8 integer ops) -- targets
// gemm's measured VALU hotspot (A-staging cast + C-epilogue) and conv's
// output pack. GEMM structure itself frozen at R7 (53us envelope).

#define NB 4
#define NS 4096
#define ND 768
#define NK 24

typedef __attribute__((ext_vector_type(8))) short short8;
typedef __attribute__((ext_vector_type(4))) float f32x4;
typedef __attribute__((ext_vector_type(4))) unsigned short u16x4;

static __device__ __forceinline__ float bf2f(unsigned short u) {
  union { unsigned int i; float f; } v; v.i = ((unsigned int)u) << 16; return v.f;
}
static __device__ __forceinline__ unsigned short f2bf(float f) {
  union { float f; unsigned int i; } v; v.f = f;
  return (unsigned short)((v.i + 0x7fffu + ((v.i >> 16) & 1u)) >> 16);
}
// HW packed convert: lo16 = bf16(lo), hi16 = bf16(hi) -- one VALU instr
static __device__ __forceinline__ unsigned int f2bf2(float lo, float hi) {
  unsigned int r;
  asm("v_cvt_pk_bf16_f32 %0, %1, %2" : "=v"(r) : "v"(lo), "v"(hi));
  return r;
}

__device__ __forceinline__ float2 cadd(float2 a, float2 b){ return make_float2(a.x+b.x, a.y+b.y); }
__device__ __forceinline__ float2 csub(float2 a, float2 b){ return make_float2(a.x-b.x, a.y-b.y); }
__device__ __forceinline__ float2 cmul(float2 a, float2 b){ return make_float2(a.x*b.x-a.y*b.y, a.x*b.y+a.y*b.x); }
// a * conj(b)
__device__ __forceinline__ float2 cmulc(float2 a, float2 b){ return make_float2(a.x*b.x+a.y*b.y, a.y*b.x-a.x*b.y); }

#define C4 0.70710678118654752f
#define C8 0.92387953251128674f
#define S8 0.38268343236508977f
#define TWO_PI 6.28318530717958648f

// DIF 16-pt: natural input, output reg r holds X[bitrev4(r)]
__device__ __forceinline__ void fft16_dif(float2 v[16]) {
  const float twr[8] = {1.f, C8, C4, S8, 0.f, -S8, -C4, -C8};
  const float twi[8] = {0.f, -S8, -C4, -C8, -1.f, -C8, -C4, -S8};
#pragma unroll
  for (int i = 0; i < 8; ++i) {                       // m=8
    float2 a = v[i], b = v[i+8];
    v[i] = cadd(a, b);
    float2 d = csub(a, b);
    v[i+8] = make_float2(d.x*twr[i]-d.y*twi[i], d.x*twi[i]+d.y*twr[i]);
  }
#pragma unroll
  for (int blk = 0; blk < 16; blk += 8)               // m=4
#pragma unroll
    for (int i = 0; i < 4; ++i) {
      float2 a = v[blk+i], b = v[blk+i+4];
      v[blk+i] = cadd(a, b);
      float2 d = csub(a, b);
      v[blk+i+4] = make_float2(d.x*twr[2*i]-d.y*twi[2*i], d.x*twi[2*i]+d.y*twr[2*i]);
    }
#pragma unroll
  for (int blk = 0; blk < 16; blk += 4) {             // m=2 (tw: 1, -i)
    { float2 a = v[blk],   b = v[blk+2]; v[blk] = cadd(a,b);   v[blk+2] = csub(a,b); }
    { float2 a = v[blk+1], b = v[blk+3]; float2 d = csub(a,b);
      v[blk+1] = cadd(a,b); v[blk+3] = make_float2(d.y, -d.x); }
  }
#pragma unroll
  for (int blk = 0; blk < 16; blk += 2) {             // m=1
    float2 a = v[blk], b = v[blk+1];
    v[blk] = cadd(a, b); v[blk+1] = csub(a, b);
  }
}

// same but input v[8..15] known zero (zero-padded signal)
__device__ __forceinline__ void fft16_dif_zero8(float2 v[16]) {
  const float twr[8] = {1.f, C8, C4, S8, 0.f, -S8, -C4, -C8};
  const float twi[8] = {0.f, -S8, -C4, -C8, -1.f, -C8, -C4, -S8};
#pragma unroll
  for (int i = 1; i < 8; ++i) {                       // m=8, b=0
    float2 a = v[i];
    v[i+8] = make_float2(a.x*twr[i]-a.y*twi[i], a.x*twi[i]+a.y*twr[i]);
  }
  v[8] = v[0];
#pragma unroll
  for (int blk = 0; blk < 16; blk += 8)               // m=4
#pragma unroll
    for (int i = 0; i < 4; ++i) {
      float2 a = v[blk+i], b = v[blk+i+4];
      v[blk+i] = cadd(a, b);
      float2 d = csub(a, b);
      v[blk+i+4] = make_float2(d.x*twr[2*i]-d.y*twi[2*i], d.x*twi[2*i]+d.y*twr[2*i]);
    }
#pragma unroll
  for (int blk = 0; blk < 16; blk += 4) {             // m=2
    { float2 a = v[blk],   b = v[blk+2]; v[blk] = cadd(a,b);   v[blk+2] = csub(a,b); }
    { float2 a = v[blk+1], b = v[blk+3]; float2 d = csub(a,b);
      v[blk+1] = cadd(a,b); v[blk+3] = make_float2(d.y, -d.x); }
  }
#pragma unroll
  for (int blk = 0; blk < 16; blk += 2) {             // m=1
    float2 a = v[blk], b = v[blk+1];
    v[blk] = cadd(a, b); v[blk+1] = csub(a, b);
  }
}

// conj-transpose mirror (unnormalized): input reg r = X[bitrev4(r)],
// output natural y[n] = sum_k X[k] W^{+nk}
__device__ __forceinline__ void idft16(float2 v[16]) {
  const float twr[8] = {1.f, C8, C4, S8, 0.f, -S8, -C4, -C8};
  const float twi[8] = {0.f, S8, C4, C8, 1.f, C8, C4, S8};     // conj
#pragma unroll
  for (int blk = 0; blk < 16; blk += 2) {             // m=1
    float2 a = v[blk], b = v[blk+1];
    v[blk] = cadd(a, b); v[blk+1] = csub(a, b);
  }
#pragma unroll
  for (int blk = 0; blk < 16; blk += 4) {             // m=2 (tw: 1, +i)
    { float2 a = v[blk],   b = v[blk+2]; v[blk] = cadd(a,b);   v[blk+2] = csub(a,b); }
    { float2 a = v[blk+1], b = v[blk+3]; float2 t = make_float2(-b.y, b.x);
      v[blk+1] = cadd(a,t); v[blk+3] = csub(a,t); }
  }
#pragma unroll
  for (int blk = 0; blk < 16; blk += 8)               // m=4
#pragma unroll
    for (int i = 0; i < 4; ++i) {
      float2 b = v[blk+i+4];
      float2 t = make_float2(b.x*twr[2*i]-b.y*twi[2*i], b.x*twi[2*i]+b.y*twr[2*i]);
      float2 a = v[blk+i];
      v[blk+i] = cadd(a, t); v[blk+i+4] = csub(a, t);
    }
#pragma unroll
  for (int i = 0; i < 8; ++i) {                       // m=8
    float2 b = v[i+8];
    float2 t = make_float2(b.x*twr[i]-b.y*twi[i], b.x*twi[i]+b.y*twr[i]);
    float2 a = v[i];
    v[i] = cadd(a, t); v[i+8] = csub(a, t);
  }
}

// idft16 but only outputs 0..7 needed: last stage skips subtract half
__device__ __forceinline__ void idft16_low8(float2 v[16]) {
  const float twr[8] = {1.f, C8, C4, S8, 0.f, -S8, -C4, -C8};
  const float twi[8] = {0.f, S8, C4, C8, 1.f, C8, C4, S8};
#pragma unroll
  for (int blk = 0; blk < 16; blk += 2) {
    float2 a = v[blk], b = v[blk+1];
    v[blk] = cadd(a, b); v[blk+1] = csub(a, b);
  }
#pragma unroll
  for (int blk = 0; blk < 16; blk += 4) {
    { float2 a = v[blk],   b = v[blk+2]; v[blk] = cadd(a,b);   v[blk+2] = csub(a,b); }
    { float2 a = v[blk+1], b = v[blk+3]; float2 t = make_float2(-b.y, b.x);
      v[blk+1] = cadd(a,t); v[blk+3] = csub(a,t); }
  }
#pragma unroll
  for (int blk = 0; blk < 16; blk += 8)
#pragma unroll
    for (int i = 0; i < 4; ++i) {
      float2 b = v[blk+i+4];
      float2 t = make_float2(b.x*twr[2*i]-b.y*twi[2*i], b.x*twi[2*i]+b.y*twr[2*i]);
      float2 a = v[blk+i];
      v[blk+i] = cadd(a, t); v[blk+i+4] = csub(a, t);
    }
#pragma unroll
  for (int i = 0; i < 8; ++i) {                       // m=8: only y[i]=a+t
    float2 b = v[i+8];
    float2 t = make_float2(b.x*twr[i]-b.y*twi[i], b.x*twi[i]+b.y*twr[i]);
    v[i] = cadd(v[i], t);
  }
}

#define BR_TABLE {0,8,4,12,2,10,6,14,1,9,5,13,3,11,7,15}
#define PAD(i) ((i) + ((i) >> 4))

// ---------------- MiT[d][e] = bf16(Mi[e][d]), LDS-tiled ----------------
__global__ __launch_bounds__(256) void transpose_cast_Mi(const float* __restrict__ Mi,
                                                         unsigned short* __restrict__ MiT) {
  __shared__ float tile[64][65];
  const int d0 = blockIdx.x * 64;
  const int e0 = blockIdx.y * 64;
  const int tid = threadIdx.x;
#pragma unroll
  for (int i = 0; i < 16; ++i) {
    int ee = (tid >> 6) + i * 4;
    int dd = tid & 63;
    tile[ee][dd] = Mi[(e0 + ee) * ND + d0 + dd];
  }
  __syncthreads();
#pragma unroll
  for (int i = 0; i < 8; ++i) {
    int dd = (tid >> 5) + i * 8;
    int ee2 = (tid & 31) * 2;
    unsigned int w = f2bf2(tile[ee2][dd], tile[ee2 + 1][dd]);
    *(unsigned int*)(MiT + (size_t)(d0 + dd) * ND + e0 + ee2) = w;
  }
}

// ---------------- GEMM (R7 structure; cvt_pk packing) ----------------
__global__ __launch_bounds__(256) void gemm_xprojT(const float* __restrict__ Xf,
                                                   const unsigned short* __restrict__ MiT,
                                                   unsigned short* __restrict__ XPT) {
  __shared__ __align__(16) unsigned char smem[33792];   // dbuf A/B (32KB) or Cb (33KB)
  unsigned short* As0 = (unsigned short*)smem;          // 4096 shorts each
  unsigned short* Bs0 = As0 + 4096;
  unsigned short* As1 = Bs0 + 4096;
  unsigned short* Bs1 = As1 + 4096;

  const int tid = threadIdx.x;
  const int lane = tid & 63;
  const int wave = tid >> 6;
  const int f = blockIdx.x;
  const int swz = (f & 7) * 96 + (f >> 3);
  const int c0 = (swz % 6) * 128;       // d
  const int r0 = (swz / 6) * 128;       // global row in [0,16384)

  const int rowA = tid >> 2;            // 0..63
  const int colq = (tid & 3) * 8;       // 0,8,16,24

  f32x4 acc[4][4];
#pragma unroll
  for (int m = 0; m < 4; ++m)
#pragma unroll
    for (int n = 0; n < 4; ++n) acc[m][n] = (f32x4){0.f, 0.f, 0.f, 0.f};

  // ---- prologue: stage tile 0 into buf0 ----
  {
    const float* ga = Xf + (size_t)(r0 + rowA) * ND + colq;
    float4 p0 = *(const float4*)ga, p1 = *(const float4*)(ga + 4);
    const float* ga2 = ga + (size_t)64 * ND;
    float4 p2 = *(const float4*)ga2, p3 = *(const float4*)(ga2 + 4);
#pragma unroll
    for (int h = 0; h < 2; ++h) {
      int c = wave * 2 + h;
      int rowc = c * 16 + (lane >> 2);
      const unsigned short* gb = MiT + (size_t)(c0 + rowc) * ND + (lane & 3) * 8;
      __builtin_amdgcn_global_load_lds(
          (const __attribute__((address_space(1))) void*)gb,
          (__attribute__((address_space(3))) void*)(Bs0 + c * 512), 16, 0, 0);
    }
    *(uint4*)(As0 + tid * 8) = make_uint4(
        f2bf2(p0.x, p0.y), f2bf2(p0.z, p0.w), f2bf2(p1.x, p1.y), f2bf2(p1.z, p1.w));
    *(uint4*)(As0 + 2048 + tid * 8) = make_uint4(
        f2bf2(p2.x, p2.y), f2bf2(p2.z, p2.w), f2bf2(p3.x, p3.y), f2bf2(p3.z, p3.w));
  }
  __syncthreads();

  for (int t = 0; t < NK; ++t) {
    unsigned short* Ac = (t & 1) ? As1 : As0;
    unsigned short* Bc = (t & 1) ? Bs1 : Bs0;
    unsigned short* An = (t & 1) ? As0 : As1;
    unsigned short* Bn = (t & 1) ? Bs0 : Bs1;
    const bool pre = (t < NK - 1);
    float4 p0, p1, p2, p3;
    if (pre) {
      const int k0n = (t + 1) * 32;
      const float* ga = Xf + (size_t)(r0 + rowA) * ND + k0n + colq;
      p0 = *(const float4*)ga; p1 = *(const float4*)(ga + 4);
      const float* ga2 = ga + (size_t)64 * ND;
      p2 = *(const float4*)ga2; p3 = *(const float4*)(ga2 + 4);
#pragma unroll
      for (int h = 0; h < 2; ++h) {
        int c = wave * 2 + h;
        int rowc = c * 16 + (lane >> 2);
        const unsigned short* gb = MiT + (size_t)(c0 + rowc) * ND + k0n + (lane & 3) * 8;
        __builtin_amdgcn_global_load_lds(
            (const __attribute__((address_space(1))) void*)gb,
            (__attribute__((address_space(3))) void*)(Bn + c * 512), 16, 0, 0);
      }
    }

    const int wr = (wave >> 1) * 64;
    const int wc = (wave & 1) * 64;
    short8 a[4], b[4];
#pragma unroll
    for (int m = 0; m < 4; ++m)
      a[m] = *(const short8*)(Ac + (wr + m * 16 + (lane & 15)) * 32 + (lane >> 4) * 8);
#pragma unroll
    for (int n = 0; n < 4; ++n)
      b[n] = *(const short8*)(Bc + (wc + n * 16 + (lane & 15)) * 32 + (lane >> 4) * 8);
#pragma unroll
    for (int m = 0; m < 4; ++m)
#pragma unroll
      for (int n = 0; n < 4; ++n)
        acc[m][n] = __builtin_amdgcn_mfma_f32_16x16x32_bf16(a[m], b[n], acc[m][n], 0, 0, 0);

    if (pre) {
      *(uint4*)(An + tid * 8) = make_uint4(
          f2bf2(p0.x, p0.y), f2bf2(p0.z, p0.w), f2bf2(p1.x, p1.y), f2bf2(p1.z, p1.w));
      *(uint4*)(An + 2048 + tid * 8) = make_uint4(
          f2bf2(p2.x, p2.y), f2bf2(p2.z, p2.w), f2bf2(p3.x, p3.y), f2bf2(p3.z, p3.w));
      __syncthreads();
    }
  }
  __syncthreads();

  unsigned int* Cb = (unsigned int*)smem;   // [128 cols][66]
  const int wr = (wave >> 1) * 64;
  const int wc = (wave & 1) * 64;
#pragma unroll
  for (int m = 0; m < 4; ++m)
#pragma unroll
    for (int n = 0; n < 4; ++n) {
      int col = wc + n * 16 + (lane & 15);
      int sp = (wr + m * 16 + (lane >> 4) * 4) >> 1;   // even
      f32x4 a4 = acc[m][n];
      *(uint2*)(Cb + col * 66 + sp) =
          make_uint2(f2bf2(a4[0], a4[1]), f2bf2(a4[2], a4[3]));
    }
  __syncthreads();
  const int bI = r0 >> 12;
  const int sBase = r0 & (NS - 1);
  {
    int col = tid >> 1, half = tid & 1;
    const unsigned int* srcl = Cb + col * 66 + half * 32;
    unsigned int* dstg = (unsigned int*)(XPT + ((size_t)bI * ND + c0 + col) * NS + sBase) + half * 32;
#pragma unroll
    for (int k = 0; k < 8; ++k)
      *(uint4*)(dstg + k * 4) = *(const uint4*)(srcl + k * 4);
  }
}

// ---------------- filter spectra (fused phi projection, LDS twiddle tables) ----------------
__global__ __launch_bounds__(256) void filter_fft(const float* __restrict__ phi,
                                                  const float* __restrict__ Mf,
                                                  float2* __restrict__ Hbr) {
  __shared__ float LR[4352], LI[4352];
  __shared__ float2 TA[256], TB[256];
  const int d = blockIdx.x;
  const int tid = threadIdx.x;
  const int BR[16] = BR_TABLE;
  float2 v[16];

  {
    float sn, cs;
    __sincosf(-(TWO_PI / 4096.f) * (float)tid, &sn, &cs); TA[tid] = make_float2(cs, sn);
    __sincosf(-(TWO_PI / 256.f) * (float)tid, &sn, &cs);  TB[tid] = make_float2(cs, sn);
  }

  float mf[NK];
#pragma unroll
  for (int k = 0; k < NK; ++k) mf[k] = Mf[k * ND + d];
#pragma unroll
  for (int n2 = 0; n2 < 8; ++n2) {
    int m = n2 * 256 + tid;            // 0..2047
    const float* pr = phi + (size_t)(2 * m) * NK;
    float acc = 0.f;
#pragma unroll
    for (int k = 0; k < NK; ++k) acc += pr[k] * mf[k];
    v[n2] = make_float2(acc, 0.f);
  }
#pragma unroll
  for (int n2 = 8; n2 < 16; ++n2) v[n2] = make_float2(0.f, 0.f);

  fft16_dif_zero8(v);
  __syncthreads();                     // tables ready
  const int t1 = tid >> 4, t0 = tid & 15;
#pragma unroll
  for (int p = 1; p < 16; ++p) v[BR[p]] = cmul(v[BR[p]], cmul(TB[p * t1], TA[p * t0]));
#pragma unroll
  for (int r = 0; r < 16; ++r) { int i = BR[r] * 256 + tid; int s = PAD(i); LR[s] = v[r].x; LI[s] = v[r].y; }
  __syncthreads();

  const int p2 = tid >> 4, n0 = tid & 15;
#pragma unroll
  for (int n1 = 0; n1 < 16; ++n1) { int i = p2 * 256 + n1 * 16 + n0; int s = PAD(i); v[n1] = make_float2(LR[s], LI[s]); }
  fft16_dif(v);
#pragma unroll
  for (int p = 1; p < 16; ++p) v[BR[p]] = cmul(v[BR[p]], TB[p * n0]);
  __syncthreads();
#pragma unroll
  for (int r = 0; r < 16; ++r) { int i = p2 * 256 + BR[r] * 16 + n0; int s = PAD(i); LR[s] = v[r].x; LI[s] = v[r].y; }
  __syncthreads();

#pragma unroll
  for (int q = 0; q < 16; ++q) { int i = tid * 16 + q; int s = PAD(i); v[q] = make_float2(LR[s], LI[s]); }
  fft16_dif(v);
  const float sc = 2.0f / 4096.0f;
  float2* H = Hbr + (size_t)d * 4096;
#pragma unroll
  for (int r = 0; r < 16; ++r)
    H[r * 256 + tid] = make_float2(v[r].x * sc, v[r].y * sc);
}

// ---------------- main conv: one (b,d) per workgroup ----------------
__global__ __launch_bounds__(256) void conv_kernel(const unsigned short* __restrict__ XPT,
                                                   const float2* __restrict__ Hbr,
                                                   unsigned int* __restrict__ outTb) {
  __shared__ float LR[4352], LI[4352];
  __shared__ float2 TA[256], TB[256];
  const int bd = blockIdx.x;
  const int d = bd % ND;
  const int tid = threadIdx.x;
  const int BR[16] = BR_TABLE;
  float2 v[16];

  {
    float sn, cs;
    __sincosf(-(TWO_PI / 4096.f) * (float)tid, &sn, &cs); TA[tid] = make_float2(cs, sn);
    __sincosf(-(TWO_PI / 256.f) * (float)tid, &sn, &cs);  TB[tid] = make_float2(cs, sn);
  }

  // load: z[n] = (x[2n], x[2n+1]) bf16 pair as one dword; n >= 2048 zero
  const unsigned int* src = (const unsigned int*)(XPT + (size_t)bd * NS);
#pragma unroll
  for (int n2 = 0; n2 < 8; ++n2) {
    unsigned int w = src[n2 * 256 + tid];
    v[n2] = make_float2(bf2f((unsigned short)(w & 0xffffu)), bf2f((unsigned short)(w >> 16)));
  }
#pragma unroll
  for (int n2 = 8; n2 < 16; ++n2) v[n2] = make_float2(0.f, 0.f);

  // ---- forward P1 ----
  fft16_dif_zero8(v);
  __syncthreads();                     // twiddle tables ready
  const int t1 = tid >> 4, t0 = tid & 15;
#pragma unroll
  for (int p = 1; p < 16; ++p) v[BR[p]] = cmul(v[BR[p]], cmul(TB[p * t1], TA[p * t0]));
#pragma unroll
  for (int r = 0; r < 16; ++r) { int i = BR[r] * 256 + tid; int s = PAD(i); LR[s] = v[r].x; LI[s] = v[r].y; }
  __syncthreads();

  // ---- forward P2 ----
  const int p2 = tid >> 4, n0 = tid & 15;
#pragma unroll
  for (int n1 = 0; n1 < 16; ++n1) { int i = p2 * 256 + n1 * 16 + n0; int s = PAD(i); v[n1] = make_float2(LR[s], LI[s]); }
  fft16_dif(v);
#pragma unroll
  for (int p = 1; p < 16; ++p) v[BR[p]] = cmul(v[BR[p]], TB[p * n0]);
  __syncthreads();
#pragma unroll
  for (int r = 0; r < 16; ++r) { int i = p2 * 256 + BR[r] * 16 + n0; int s = PAD(i); LR[s] = v[r].x; LI[s] = v[r].y; }
  __syncthreads();

  // ---- forward P3 + pointwise*H + inverse PA: all in registers ----
#pragma unroll
  for (int q = 0; q < 16; ++q) { int i = tid * 16 + q; int s = PAD(i); v[q] = make_float2(LR[s], LI[s]); }
  fft16_dif(v);
  const float2* H = Hbr + (size_t)d * 4096;
#pragma unroll
  for (int r = 0; r < 16; ++r) v[r] = cmul(v[r], H[r * 256 + tid]);
  idft16(v);                                   // -> natural over pc-axis
#pragma unroll
  for (int n = 1; n < 16; ++n) v[n] = cmulc(v[n], TB[n * (tid & 15)]);
#pragma unroll
  for (int n = 0; n < 16; ++n) { int i = tid * 16 + n; int s = PAD(i); LR[s] = v[n].x; LI[s] = v[n].y; }
  __syncthreads();

  // ---- inverse PB: thread (pa,n0), IDFT over pb -> n1 ----
#pragma unroll
  for (int r = 0; r < 16; ++r) { int i = p2 * 256 + BR[r] * 16 + n0; int s = PAD(i); v[r] = make_float2(LR[s], LI[s]); }
  idft16(v);                                   // -> natural n1
  {
    float2 cA = TA[p2 * n0];
#pragma unroll
    for (int n = 0; n < 16; ++n) v[n] = cmulc(v[n], cmul(TB[p2 * n], cA));
  }
  __syncthreads();
#pragma unroll
  for (int n = 0; n < 16; ++n) { int i = p2 * 256 + n * 16 + n0; int s = PAD(i); LR[s] = v[n].x; LI[s] = v[n].y; }
  __syncthreads();

  // ---- inverse PC: thread tid, IDFT over pa -> natural n2 (only n2<8 needed) ----
#pragma unroll
  for (int r = 0; r < 16; ++r) { int i = BR[r] * 256 + tid; int s = PAD(i); v[r] = make_float2(LR[s], LI[s]); }
  idft16_low8(v);
  unsigned int* dst = outTb + (size_t)bd * 2048;    // dword = (out[2n], out[2n+1]) bf16
#pragma unroll
  for (int n2 = 0; n2 < 8; ++n2) {
    float2 y = v[n2];
    dst[(n2 << 8) + tid] = f2bf2(y.x, y.y);
  }
}

// ---------------- transpose outTb (B,D,S) bf16 -> out (B,S,D) fp32 ----------------
__global__ __launch_bounds__(256) void transpose_out(const unsigned int* __restrict__ outTb,
                                                     float* __restrict__ out) {
  __shared__ float tile[64][65];
  const int b = blockIdx.z;
  const int d0 = blockIdx.y * 64;
  const int s0 = blockIdx.x * 64;
  const int tid = threadIdx.x;
#pragma unroll
  for (int i = 0; i < 8; ++i) {
    int dd = (tid >> 5) + i * 8;
    int ss2 = (tid & 31) * 2;
    unsigned int w = outTb[(((size_t)b * ND + d0 + dd) * NS + s0 + ss2) >> 1];
    tile[dd][ss2]     = bf2f((unsigned short)(w & 0xffffu));
    tile[dd][ss2 + 1] = bf2f((unsigned short)(w >> 16));
  }
  __syncthreads();
#pragma unroll
  for (int i = 0; i < 16; ++i) {
    int ss = (tid >> 6) + i * 4;
    int dd = tid & 63;
    out[((size_t)b * NS + s0 + ss) * ND + d0 + dd] = tile[dd][ss];
  }
}

extern "C" void kernel_launch(void* const* d_in, const int* in_sizes, int n_in,
                              void* d_out, int out_size, void* d_ws, size_t ws_size,
                              hipStream_t stream) {
  const float* x   = (const float*)d_in[0];
  const float* phi = (const float*)d_in[1];
  const float* Mi  = (const float*)d_in[2];
  const float* Mf  = (const float*)d_in[3];
  float* out = (float*)d_out;

  // ws (96 MB): XPT bf16 @0 (24M) | Hbr @24M (24M) | pool @48M (48M)
  // pool: outTb bf16 @0 (24M) | MiT @24M
  const size_t SZ_XPT = (size_t)NB * ND * NS * 2;        // 24 MB
  const size_t SZ_HBR = (size_t)ND * 4096 * 8;           // 24 MB
  const size_t SZ_POOL = (size_t)NB * ND * NS * 4;       // 48 MB
  if (ws_size < SZ_XPT + SZ_HBR + SZ_POOL) return;

  char* ws = (char*)d_ws;
  unsigned short* xprojT = (unsigned short*)ws;
  float2* Hbr = (float2*)(ws + SZ_XPT);
  char* pool = ws + SZ_XPT + SZ_HBR;
  unsigned int* outTb = (unsigned int*)pool;
  unsigned short* MiT = (unsigned short*)(pool + 25165824);

  transpose_cast_Mi<<<dim3(ND / 64, ND / 64), 256, 0, stream>>>(Mi, MiT);
  gemm_xprojT<<<768, 256, 0, stream>>>(x, MiT, xprojT);
  filter_fft<<<ND, 256, 0, stream>>>(phi, Mf, Hbr);
  conv_kernel<<<NB * ND, 256, 0, stream>>>(xprojT, Hbr, outTb);
  transpose_out<<<dim3(NS / 64, ND / 64, NB), 256, 0, stream>>>(outTb, out);
}